// Round 6
// baseline (305.197 us; speedup 1.0000x reference)
//
#include <hip/hip_runtime.h>
#include <math.h>

#define IMG 112
#define CIN 64
#define CH 256
#define PADW 114
#define IMG2 12544   // 112*112
#define NPIX 25088   // 2*112*112
#define SCQ 0.17677669529663687f

typedef __bf16 bf16;
typedef __bf16 bf16x8 __attribute__((ext_vector_type(8)));
typedef float f32x4 __attribute__((ext_vector_type(4)));

__device__ __forceinline__ void gld_lds16(const void* g, void* l) {
    __builtin_amdgcn_global_load_lds(
        (const __attribute__((address_space(1))) void*)g,
        (__attribute__((address_space(3))) void*)l,
        16, 0, 0);
}
#define VMCNT0() asm volatile("s_waitcnt vmcnt(0)" ::: "memory")
#define BAR() __builtin_amdgcn_s_barrier()

// ---------------- prep: pad images (+zero borders) + all weight transposes ----------------
__global__ __launch_bounds__(256) void prep_kernel(
    const float* __restrict__ xq, const float* __restrict__ xkv,
    bf16* __restrict__ padq, bf16* __restrict__ padkv,
    const float* __restrict__ c1w, const float* __restrict__ c3w,
    bf16* __restrict__ cw1, bf16* __restrict__ cw2,
    const float* __restrict__ wq, bf16* __restrict__ wqt,
    const float* __restrict__ wkv, bf16* __restrict__ wkvt,
    const float* __restrict__ wp, bf16* __restrict__ wpt,
    const float* __restrict__ f1w, bf16* __restrict__ wf1,
    const float* __restrict__ f2w, bf16* __restrict__ wf2) {
    int bid = blockIdx.x, tid = threadIdx.x;
    __shared__ float lds[CIN * 113];
    if (bid < 448) {
        const float* in = (bid < 224) ? xq : xkv;
        bf16* out = (bid < 224) ? padq : padkv;
        int bi = (bid < 224) ? bid : bid - 224;
        int b = bi / IMG, i = bi % IMG;
        const float* src = in + (size_t)b * CIN * IMG2 + (size_t)i * IMG;
        for (int t = tid; t < CIN * IMG; t += 256) {
            int ci = t / IMG, j = t - ci * IMG;
            lds[ci * 113 + j] = src[(size_t)ci * IMG2 + j];
        }
        __syncthreads();
        bf16* dst = out + (((size_t)(b * PADW + (i + 1)) * PADW) + 1) * CIN;
        for (int t = tid; t < CIN * IMG; t += 256) {
            int j = t / CIN, ci = t - j * CIN;
            dst[(size_t)j * CIN + ci] = (bf16)lds[ci * 113 + j];
        }
        // border zeroing: cols 0 and 113 of this padded row
        bf16* rowbase = out + ((size_t)(b * PADW + (i + 1)) * PADW) * CIN;
        if (tid < 128) rowbase[(tid >> 6 ? 113 * CIN : 0) + (tid & 63)] = (bf16)0.0f;
        if (i == 0)
            for (int t = tid; t < PADW * CIN; t += 256)
                out[((size_t)(b * PADW + 0) * PADW) * CIN + t] = (bf16)0.0f;
        if (i == IMG - 1)
            for (int t = tid; t < PADW * CIN; t += 256)
                out[((size_t)(b * PADW + 113) * PADW) * CIN + t] = (bf16)0.0f;
    } else if (bid < 1024) {
        int idx = (bid - 448) * 256 + tid;   // 147456 = 576 blocks
        int co = idx / 576, r = idx - co * 576;
        int tap = r >> 6, ci = r & 63;
        int src = co * 576 + ci * 9 + tap;
        cw1[idx] = (bf16)c1w[src];
        cw2[idx] = (bf16)c3w[src];
    } else {
        int off = (bid - 1024) * 256 + tid;  // 524288 = 2048 blocks
        const float* in; bf16* out; int K, N; float sc = 1.0f; int base;
        if (off < 65536)       { in = wq;  out = wqt;  K = 256; N = 256; sc = SCQ; base = 0; }
        else if (off < 196608) { in = wkv; out = wkvt; K = 256; N = 512; base = 65536; }
        else if (off < 262144) { in = wp;  out = wpt;  K = 256; N = 256; base = 196608; }
        else if (off < 393216) { in = f1w; out = wf1;  K = 256; N = 512; base = 262144; }
        else                   { in = f2w; out = wf2;  K = 512; N = 256; base = 393216; }
        int idx = off - base;
        int n = idx / K, k = idx - n * K;
        out[idx] = (bf16)(in[(size_t)k * N + n] * sc);
    }
}

// ---------------- fused GEMM core: 64x256 tile, BK=64, 4 waves (2x2 -> 32x128/wave) ----------------
// Single-buffered staging (40KB) + epilogue transpose buffer REUSES staging LDS.
// MODE: 0=dense bf16 out; 1=LN->two bf16 outs; 2=res+out0(raw)+LN->out1; 3=gelu->bf16; 4=f32 NCHW + res
#define M_DENSE 0
#define M_LN2   1
#define M_WPLN  2
#define M_GELU  3
#define M_NCHW  4
#define TS 264   // bf16 T stride (16B-multiple), col XOR-swizzled
#define TFS 258  // f32 T stride (NCHW path, 32-row passes)

template <int AMODE, int MODE>
__device__ __forceinline__ void gemm_core(
    char* sm,
    const bf16* __restrict__ A, const bf16* __restrict__ B,
    const float* __restrict__ bias, float bscale,
    const bf16* __restrict__ res,
    bf16* __restrict__ out0, int ldo0,
    bf16* __restrict__ out1, float* __restrict__ outf,
    const float* __restrict__ lnw0, const float* __restrict__ lnb0,
    const float* __restrict__ lnw1, const float* __restrict__ lnb1,
    int K) {
    bf16* As = (bf16*)sm;              // [64*64]  8 KB  (single-buffered)
    bf16* Bs = (bf16*)(sm + 8192);     // [256*64] 32 KB
    float* lnb = (float*)sm;           // 1 KB, live only after K-loop
    bf16* Tb = (bf16*)(sm + 2048);     // [64][TS] 33.8 KB, after K-loop
    float* Tf = (float*)(sm + 2048);   // [32][TFS] 33 KB, after K-loop (NCHW)

    const int tid = threadIdx.x;
    const int wave = tid >> 6, lane = tid & 63;
    const int m0 = blockIdx.x * 64;
    const int wm = wave >> 1, wn = wave & 1;
    const int fr = lane & 15, fq = lane >> 4;
    const int srow = lane >> 3;
    const int scol = ((lane & 7) ^ srow) * 8;   // inverse-swizzled source chunk (staging)

    const bf16* aptr[2];
#pragma unroll
    for (int q = 0; q < 2; ++q) {
        int arow = m0 + wave * 16 + q * 8 + srow;
        if (AMODE == 1) {
            int b = arow / IMG2;
            int rem = arow - b * IMG2;
            int i = rem / IMG, j = rem - i * IMG;
            aptr[q] = A + ((size_t)((b * PADW + i) * PADW + j)) * CIN + scol;
        } else {
            aptr[q] = A + (size_t)arow * K + scol;
        }
    }
    const bf16* bptr0 = B + (size_t)(wave * 64 + srow) * K + scol;

    auto STAGE = [&](int kt) {
        int aoff = (AMODE == 1) ? ((kt / 3) * PADW + (kt - (kt / 3) * 3)) * CIN : kt * 64;
        int boff = kt * 64;
        bf16* ad = As + (wave * 16) * 64;
        gld_lds16(aptr[0] + aoff, ad);
        gld_lds16(aptr[1] + aoff, ad + 8 * 64);
        bf16* bd = Bs + (wave * 64) * 64;
#pragma unroll
        for (int u = 0; u < 8; ++u)
            gld_lds16(bptr0 + (size_t)u * 8 * K + boff, bd + u * 8 * 64);
    };

    f32x4 acc[2][8] = {};
    auto COMPUTE = [&]() {
#pragma unroll
        for (int ks = 0; ks < 2; ++ks) {
            int ch = ((ks * 4 + fq) ^ (fr & 7)) * 8;
            bf16x8 af[2];
#pragma unroll
            for (int mi = 0; mi < 2; ++mi) af[mi] = *(const bf16x8*)&As[(wm * 32 + mi * 16 + fr) * 64 + ch];
            bf16x8 bv[8];
#pragma unroll
            for (int ni = 0; ni < 8; ++ni) bv[ni] = *(const bf16x8*)&Bs[(wn * 128 + ni * 16 + fr) * 64 + ch];
#pragma unroll
            for (int mi = 0; mi < 2; ++mi)
#pragma unroll
                for (int ni = 0; ni < 8; ++ni)
                    acc[mi][ni] = __builtin_amdgcn_mfma_f32_16x16x32_bf16(af[mi], bv[ni], acc[mi][ni], 0, 0, 0);
        }
    };

    const int nk = K >> 6;
    for (int kt = 0; kt < nk; ++kt) {
        STAGE(kt);
        VMCNT0();
        BAR();
        COMPUTE();
        BAR();           // staging (and, after last iter, the T/lnb overlay) is safe to overwrite
    }

    // ---- epilogue in acc-space: bias (+res) (+gelu) ----
    float bvv[8];
#pragma unroll
    for (int ni = 0; ni < 8; ++ni) bvv[ni] = bias[wn * 128 + ni * 16 + fr] * bscale;
#pragma unroll
    for (int mi = 0; mi < 2; ++mi)
#pragma unroll
        for (int ni = 0; ni < 8; ++ni)
#pragma unroll
            for (int r = 0; r < 4; ++r) {
                float x = acc[mi][ni][r] + bvv[ni];
                if (MODE == M_WPLN) {
                    int prow = m0 + wm * 32 + mi * 16 + fq * 4 + r;
                    int col = wn * 128 + ni * 16 + fr;
                    x += (float)res[(size_t)prow * 256 + col];
                }
                if (MODE == M_GELU) x = 0.5f * x * (1.0f + erff(x * 0.70710678118f));
                acc[mi][ni][r] = x;
            }

    // ---- LN stats (M_LN2, M_WPLN) ----
    float mean_[2][4], rstd_[2][4];
    if (MODE == M_LN2 || MODE == M_WPLN) {
#pragma unroll
        for (int mi = 0; mi < 2; ++mi)
#pragma unroll
            for (int r = 0; r < 4; ++r) {
                float s = 0.0f, ss = 0.0f;
#pragma unroll
                for (int ni = 0; ni < 8; ++ni) {
                    float x = acc[mi][ni][r];
                    s += x; ss += x * x;
                }
#pragma unroll
                for (int msk = 1; msk <= 8; msk <<= 1) {
                    s += __shfl_xor(s, msk);
                    ss += __shfl_xor(ss, msk);
                }
                if (fr == 0) {
                    int row = wm * 32 + mi * 16 + fq * 4 + r;
                    lnb[wn * 128 + row] = s;
                    lnb[wn * 128 + 64 + row] = ss;
                }
            }
        BAR();
#pragma unroll
        for (int mi = 0; mi < 2; ++mi)
#pragma unroll
            for (int r = 0; r < 4; ++r) {
                int row = wm * 32 + mi * 16 + fq * 4 + r;
                float s = lnb[row] + lnb[128 + row];
                float ss = lnb[64 + row] + lnb[192 + row];
                float mean = s * (1.0f / CH);
                float var = ss * (1.0f / CH) - mean * mean;
                mean_[mi][r] = mean;
                rstd_[mi][r] = rsqrtf(var + 1e-5f);
            }
    }

    if (MODE == M_NCHW) {
        // two 32-row passes through f32 Tf; waves wm==p own pass p's rows
        int c = tid;                             // output channel 0..255
        int b = m0 / IMG2, p0 = m0 - b * IMG2;
        float* outp = outf + ((size_t)(b * CH + c)) * IMG2 + p0;
        const bf16* rp = res + (size_t)m0 * 256 + c;
#pragma unroll
        for (int p = 0; p < 2; ++p) {
            if (wm == p) {
#pragma unroll
                for (int mi = 0; mi < 2; ++mi)
#pragma unroll
                    for (int ni = 0; ni < 8; ++ni)
#pragma unroll
                        for (int r = 0; r < 4; ++r)
                            Tf[(mi * 16 + fq * 4 + r) * TFS + wn * 128 + ni * 16 + fr] = acc[mi][ni][r];
            }
            BAR();
#pragma unroll
            for (int g = 0; g < 8; ++g) {
                f32x4 v;
#pragma unroll
                for (int e = 0; e < 4; ++e)
                    v[e] = Tf[(g * 4 + e) * TFS + c] + (float)rp[(size_t)(p * 32 + g * 4 + e) * 256];
                *(f32x4*)(outp + p * 32 + g * 4) = v;
            }
            BAR();
        }
    } else {
        // bf16 transpose buffer with T2 col-XOR swizzle
#pragma unroll
        for (int mi = 0; mi < 2; ++mi)
#pragma unroll
            for (int ni = 0; ni < 8; ++ni)
#pragma unroll
                for (int r = 0; r < 4; ++r) {
                    int row = wm * 32 + mi * 16 + fq * 4 + r;
                    int col = wn * 128 + ni * 16 + fr;
                    float x = acc[mi][ni][r];
                    if (MODE == M_LN2) x = (x - mean_[mi][r]) * rstd_[mi][r];
                    Tb[row * TS + (col ^ ((row & 7) << 3))] = (bf16)x;
                }
        BAR();
        int row = tid & 63, qd = tid >> 6;       // each wave stores one 64-col quarter
        int cb = qd * 64;
        int xr = (row & 7) << 3;
        if (MODE == M_DENSE || MODE == M_GELU) {
            bf16* op = out0 + (size_t)(m0 + row) * ldo0 + cb;
#pragma unroll
            for (int g = 0; g < 8; ++g)
                *(bf16x8*)(op + g * 8) = *(const bf16x8*)&Tb[row * TS + ((cb + g * 8) ^ xr)];
        } else if (MODE == M_LN2) {
            bf16* op0 = out0 + (size_t)(m0 + row) * 256 + cb;
            bf16* op1 = out1 + (size_t)(m0 + row) * 256 + cb;
#pragma unroll
            for (int g = 0; g < 8; ++g) {
                bf16x8 xh = *(const bf16x8*)&Tb[row * TS + ((cb + g * 8) ^ xr)];
                bf16x8 o0, o1;
#pragma unroll
                for (int e = 0; e < 8; ++e) {
                    int c = cb + g * 8 + e;
                    float v = (float)xh[e];
                    o0[e] = (bf16)(v * lnw0[c] + lnb0[c]);
                    o1[e] = (bf16)(v * lnw1[c] + lnb1[c]);
                }
                *(bf16x8*)(op0 + g * 8) = o0;
                *(bf16x8*)(op1 + g * 8) = o1;
            }
        } else if (MODE == M_WPLN) {
            float s = lnb[row] + lnb[128 + row];
            float ss = lnb[64 + row] + lnb[192 + row];
            float mean = s * (1.0f / CH);
            float rstd = rsqrtf(ss * (1.0f / CH) - mean * mean + 1e-5f);
            bf16* op0 = out0 + (size_t)(m0 + row) * 256 + cb;   // ATT (raw)
            bf16* op1 = out1 + (size_t)(m0 + row) * 256 + cb;   // H (normalized)
#pragma unroll
            for (int g = 0; g < 8; ++g) {
                bf16x8 xv = *(const bf16x8*)&Tb[row * TS + ((cb + g * 8) ^ xr)];
                bf16x8 o1;
#pragma unroll
                for (int e = 0; e < 8; ++e) {
                    int c = cb + g * 8 + e;
                    o1[e] = (bf16)(((float)xv[e] - mean) * rstd * lnw0[c] + lnb0[c]);
                }
                *(bf16x8*)(op0 + g * 8) = xv;
                *(bf16x8*)(op1 + g * 8) = o1;
            }
        }
    }
}

// ---------------- wrapper kernels ----------------
#define SMEMSZ 40960

__global__ __launch_bounds__(256, 3) void conv_kernel(
    const bf16* padq, const bf16* padkv, const bf16* cw1, const bf16* cw2,
    const float* c1b, const float* c3b,
    bf16* qn, bf16* kvn, bf16* x3,
    const float* l1w, const float* l1b, const float* l10w, const float* l10b) {
    __shared__ __align__(16) char sm[SMEMSZ];
    if (blockIdx.y == 0)
        gemm_core<1, M_LN2>(sm, padq, cw1, c1b, 1.0f, nullptr, qn, 256, kvn, nullptr,
                            l1w, l1b, l10w, l10b, 576);
    else
        gemm_core<1, M_DENSE>(sm, padkv, cw2, c3b, 1.0f, nullptr, x3, 256, nullptr, nullptr,
                              nullptr, nullptr, nullptr, nullptr, 576);
}

__global__ __launch_bounds__(256, 3) void qkv_kernel(
    const bf16* qnp, const bf16* kvnp, const bf16* wqt, const bf16* wkvt,
    const float* bq, const float* bkv, bf16* q, bf16* kv) {
    __shared__ __align__(16) char sm[SMEMSZ];
    int by = blockIdx.y;
    const bf16* A = by ? kvnp : qnp;
    const bf16* B = by ? (wkvt + (size_t)(by - 1) * 65536) : wqt;
    const float* bias = by ? (bkv + (by - 1) * 256) : bq;
    float bsc = by ? 1.0f : SCQ;
    bf16* out = by ? (kv + (by - 1) * 256) : q;
    int ldo = by ? 512 : 256;
    gemm_core<0, M_DENSE>(sm, A, B, bias, bsc, nullptr, out, ldo, nullptr, nullptr,
                          nullptr, nullptr, nullptr, nullptr, 256);
}

__global__ __launch_bounds__(256, 3) void wp_kernel(
    const bf16* ao, const bf16* wpt, const float* bp, const bf16* x3,
    bf16* att, bf16* h, const float* l3w, const float* l3b) {
    __shared__ __align__(16) char sm[SMEMSZ];
    gemm_core<0, M_WPLN>(sm, ao, wpt, bp, 1.0f, x3, att, 256, h, nullptr,
                         l3w, l3b, nullptr, nullptr, 256);
}

__global__ __launch_bounds__(256, 3) void fc1_kernel(
    const bf16* h, const bf16* wf1, const float* f1b, bf16* m1) {
    __shared__ __align__(16) char sm[SMEMSZ];
    int by = blockIdx.y;
    gemm_core<0, M_GELU>(sm, h, wf1 + (size_t)by * 65536, f1b + by * 256, 1.0f, nullptr,
                         m1 + by * 256, 512, nullptr, nullptr,
                         nullptr, nullptr, nullptr, nullptr, 256);
}

__global__ __launch_bounds__(256, 3) void fc2_kernel(
    const bf16* m1, const bf16* wf2, const float* f2b, const bf16* att, float* out) {
    __shared__ __align__(16) char sm[SMEMSZ];
    gemm_core<0, M_NCHW>(sm, m1, wf2, f2b, 1.0f, att, nullptr, 0, nullptr, out,
                         nullptr, nullptr, nullptr, nullptr, 512);
}

// ---------------- neighborhood attention (3x3 window, 8 heads, hd=32) ----------------
__global__ __launch_bounds__(256) void attn_kernel(const bf16* __restrict__ q, const bf16* __restrict__ kv,
                                                   const float* __restrict__ rpb, bf16* __restrict__ out) {
    int idx = blockIdx.x * 256 + threadIdx.x;   // 25088*8 total
    int h = idx & 7, p = idx >> 3;
    int b = p / IMG2;
    int rem = p - b * IMG2;
    int i = rem / IMG, j = rem - i * IMG;
    int si = i - 1; if (si < 0) si = 0; if (si > IMG - 3) si = IMG - 3;
    int sj = j - 1; if (sj < 0) sj = 0; if (sj > IMG - 3) sj = IMG - 3;
    int pi = i - si, pj = j - sj;

    float qv[32];
    {
        const bf16x8* qp = (const bf16x8*)(q + (size_t)p * CH + h * 32);
#pragma unroll
        for (int g = 0; g < 4; ++g) {
            bf16x8 t = qp[g];
#pragma unroll
            for (int e = 0; e < 8; ++e) qv[g * 8 + e] = (float)t[e];
        }
    }
    float logits[9];
#pragma unroll
    for (int a = 0; a < 3; ++a) {
#pragma unroll
        for (int bb = 0; bb < 3; ++bb) {
            int pn = (b * IMG + (si + a)) * IMG + (sj + bb);
            const bf16x8* kp = (const bf16x8*)(kv + (size_t)pn * 512 + h * 32);
            float s = 0.0f;
#pragma unroll
            for (int g = 0; g < 4; ++g) {
                bf16x8 t = kp[g];
#pragma unroll
                for (int e = 0; e < 8; ++e) s += qv[g * 8 + e] * (float)t[e];
            }
            logits[a * 3 + bb] = s + rpb[(h * 5 + (a - pi + 2)) * 5 + (bb - pj + 2)];
        }
    }
    float mx = logits[0];
#pragma unroll
    for (int n = 1; n < 9; ++n) mx = fmaxf(mx, logits[n]);
    float den = 0.0f;
#pragma unroll
    for (int n = 0; n < 9; ++n) { logits[n] = expf(logits[n] - mx); den += logits[n]; }
    float inv = 1.0f / den;
    float o[32] = {};
#pragma unroll
    for (int a = 0; a < 3; ++a) {
#pragma unroll
        for (int bb = 0; bb < 3; ++bb) {
            int pn = (b * IMG + (si + a)) * IMG + (sj + bb);
            float wgt = logits[a * 3 + bb] * inv;
            const bf16x8* vp = (const bf16x8*)(kv + (size_t)pn * 512 + 256 + h * 32);
#pragma unroll
            for (int g = 0; g < 4; ++g) {
                bf16x8 t = vp[g];
#pragma unroll
                for (int e = 0; e < 8; ++e) o[g * 8 + e] += wgt * (float)t[e];
            }
        }
    }
    bf16* op = out + (size_t)p * CH + h * 32;
#pragma unroll
    for (int g = 0; g < 4; ++g) {
        bf16x8 t;
#pragma unroll
        for (int e = 0; e < 8; ++e) t[e] = (bf16)o[g * 8 + e];
        *(bf16x8*)(op + g * 8) = t;
    }
}

extern "C" void kernel_launch(void* const* d_in, const int* in_sizes, int n_in,
                              void* d_out, int out_size, void* d_ws, size_t ws_size,
                              hipStream_t stream) {
    (void)in_sizes; (void)n_in; (void)out_size; (void)ws_size;
    const float* xq    = (const float*)d_in[0];
    const float* xkv   = (const float*)d_in[1];
    const float* c1w   = (const float*)d_in[2];
    const float* c1b   = (const float*)d_in[3];
    const float* c3w   = (const float*)d_in[4];
    const float* c3b   = (const float*)d_in[5];
    const float* ln1w  = (const float*)d_in[6];
    const float* ln1b  = (const float*)d_in[7];
    const float* ln10w = (const float*)d_in[8];
    const float* ln10b = (const float*)d_in[9];
    const float* ln3w  = (const float*)d_in[10];
    const float* ln3b  = (const float*)d_in[11];
    const float* wq    = (const float*)d_in[12];
    const float* bq    = (const float*)d_in[13];
    const float* wkv   = (const float*)d_in[14];
    const float* bkv   = (const float*)d_in[15];
    const float* rpb   = (const float*)d_in[16];
    const float* wp    = (const float*)d_in[17];
    const float* bp    = (const float*)d_in[18];
    const float* f1w   = (const float*)d_in[19];
    const float* f1b   = (const float*)d_in[20];
    const float* f2w   = (const float*)d_in[21];
    const float* f2b   = (const float*)d_in[22];
    float* out = (float*)d_out;

    char* ws = (char*)d_ws;
    bf16* PADQ  = (bf16*)(ws + 0);           // 3,326,976
    bf16* PADKV = (bf16*)(ws + 3326976);     // 3,326,976
    bf16* CW1   = (bf16*)(ws + 6653952);     //   294,912
    bf16* CW2   = (bf16*)(ws + 6948864);     //   294,912
    bf16* WQT   = (bf16*)(ws + 7243776);     //   131,072
    bf16* WKVT  = (bf16*)(ws + 7374848);     //   262,144
    bf16* WPT   = (bf16*)(ws + 7636992);     //   131,072
    bf16* WF1   = (bf16*)(ws + 7768064);     //   262,144
    bf16* WF2   = (bf16*)(ws + 8030208);     //   262,144
    bf16* QN    = (bf16*)(ws + 8292352);     // 12,845,056
    bf16* KVN   = (bf16*)(ws + 21137408);    // 12,845,056
    bf16* Q     = (bf16*)(ws + 33982464);    // 12,845,056
    bf16* KV    = (bf16*)(ws + 46827520);    // 25,690,112
    bf16* AO    = (bf16*)(ws + 72517632);    // 12,845,056
    bf16* X3    = (bf16*)(ws + 85362688);    // 12,845,056
    bf16* ATT   = (bf16*)(ws + 98207744);    // 12,845,056
    bf16* H     = (bf16*)(ws + 111052800);   // 12,845,056
    bf16* M1    = (bf16*)(ws + 123897856);   // 25,690,112 -> total 149,587,968

    prep_kernel<<<3072, 256, 0, stream>>>(xq, xkv, PADQ, PADKV, c1w, c3w, CW1, CW2,
                                          wq, WQT, wkv, WKVT, wp, WPT, f1w, WF1, f2w, WF2);
    conv_kernel<<<dim3(392, 2), 256, 0, stream>>>(PADQ, PADKV, CW1, CW2, c1b, c3b,
                                                  QN, KVN, X3, ln1w, ln1b, ln10w, ln10b);
    qkv_kernel<<<dim3(392, 3), 256, 0, stream>>>(QN, KVN, WQT, WKVT, bq, bkv, Q, KV);
    attn_kernel<<<784, 256, 0, stream>>>(Q, KV, rpb, AO);
    wp_kernel<<<392, 256, 0, stream>>>(AO, WPT, bp, X3, ATT, H, ln3w, ln3b);
    fc1_kernel<<<dim3(392, 2), 256, 0, stream>>>(H, WF1, f1b, M1);
    fc2_kernel<<<392, 256, 0, stream>>>(M1, WF2, f2b, ATT, out);
}